// Round 4
// baseline (30.296 us; speedup 1.0000x reference)
//
#include <hip/hip_runtime.h>

// Problem constants (shapes fixed by setup_inputs).
#define NCLASSES 5
#define MS 8
#define NC 128          // channels
#define HW (256 * 256)  // H*W
#define BLK 512         // threads per block (8 waves); 512 blocks -> 2 blocks/CU, 16 waves/CU

// Per pixel: out[m] = relu( dot(image[b,:,h,w], W[l,m,:]) + b[l,m] ), l = cluster label.
// W staged in LDS as [c][l][m]: the 8 m-values for (c,l) are two 16B float4 reads
// (2x ds_read_b128, <=5 distinct addresses/wave -> broadcast-dominated, ~2-way max
// aliasing = free per m136). PPT=1: each image load is one fully-coalesced 256B wave
// transaction; unroll 16 keeps ~16 loads in flight/wave (~64KB/CU >> 9KB needed to
// cover ~900cy HBM latency at 10B/cyc/CU).
__global__ __launch_bounds__(BLK, 4) void clusterdown_kernel(
    const float* __restrict__ image,      // (B, C, H, W)
    const int* __restrict__ clusters,     // (B, 1, H, W) int32
    const float* __restrict__ Wg,         // (NCLASSES, MS, NC)
    const float* __restrict__ bg,         // (NCLASSES, MS)
    float* __restrict__ out,              // (B, MS, H, W)
    int n_pix)
{
    __shared__ float wlds[NC * NCLASSES * MS]; // 20 KiB, [c][l][m]
    __shared__ float blds[NCLASSES * MS];

    const int tid = threadIdx.x;

    // Stage W with float4 global loads: 5120 floats = 1280 float4s.
    // flat i = l*1024 + m*128 + c  (MS*NC = 1024, NC = 128 -> shifts/masks)
    for (int j = tid; j < (NCLASSES * MS * NC) / 4; j += BLK) {
        const float4 w4 = ((const float4*)Wg)[j];
        const int i = j * 4;
        const int l = i >> 10;
        const int m = (i >> 7) & (MS - 1);
        const int c = i & (NC - 1);
        wlds[((c + 0) * NCLASSES + l) * MS + m] = w4.x;
        wlds[((c + 1) * NCLASSES + l) * MS + m] = w4.y;
        wlds[((c + 2) * NCLASSES + l) * MS + m] = w4.z;
        wlds[((c + 3) * NCLASSES + l) * MS + m] = w4.w;
    }
    if (tid < NCLASSES * MS) blds[tid] = bg[tid];
    __syncthreads();

    const int p = blockIdx.x * BLK + tid;
    if (p >= n_pix) return;

    const int bidx = p / HW;
    const int hw   = p - bidx * HW;

    const int lab = clusters[p];
    const bool valid = (lab >= 0) && (lab < NCLASSES);
    const int l = valid ? lab : 0;

    float acc[MS];
#pragma unroll
    for (int m = 0; m < MS; ++m) acc[m] = blds[l * MS + m];

    const float* ip = image + (size_t)bidx * NC * HW + hw;

#pragma unroll 16
    for (int c = 0; c < NC; ++c) {
        const float v = ip[(size_t)c * HW];
        const float4* wp = (const float4*)&wlds[(c * NCLASSES + l) * MS];
        const float4 w0 = wp[0];
        const float4 w1 = wp[1];
        acc[0] = fmaf(v, w0.x, acc[0]);
        acc[1] = fmaf(v, w0.y, acc[1]);
        acc[2] = fmaf(v, w0.z, acc[2]);
        acc[3] = fmaf(v, w0.w, acc[3]);
        acc[4] = fmaf(v, w1.x, acc[4]);
        acc[5] = fmaf(v, w1.y, acc[5]);
        acc[6] = fmaf(v, w1.z, acc[6]);
        acc[7] = fmaf(v, w1.w, acc[7]);
    }

    float* op = out + (size_t)bidx * MS * HW + hw;
#pragma unroll
    for (int m = 0; m < MS; ++m) {
        const float r = valid ? fmaxf(acc[m], 0.0f) : 0.0f;
        op[(size_t)m * HW] = r;
    }
}

extern "C" void kernel_launch(void* const* d_in, const int* in_sizes, int n_in,
                              void* d_out, int out_size, void* d_ws, size_t ws_size,
                              hipStream_t stream) {
    const float* image  = (const float*)d_in[0];
    const int* clusters = (const int*)d_in[1];
    const float* Wg     = (const float*)d_in[2];
    const float* bg     = (const float*)d_in[3];
    float* out          = (float*)d_out;

    const int n_pix = in_sizes[1]; // B*H*W
    const int grid  = (n_pix + BLK - 1) / BLK;

    clusterdown_kernel<<<grid, BLK, 0, stream>>>(image, clusters, Wg, bg, out, n_pix);
}